// Round 2
// baseline (337.522 us; speedup 1.0000x reference)
//
#include <hip/hip_runtime.h>
#include <math.h>

// x:    [B=8, C=4, H=256, W=256] f32
// filt: [B, C*25, H, W]          f32
// out:  [B, 1, H, W]             f32
// out[b,h,w] = tanh( sum_{c,p} x_pad[b,c,h+p/5-2, w+p%5-2] * filt[b,c*25+p,h,w] )
//
// Round-1 post-mortem: deep async DMA pipelining (>=120KB in flight/CU) changed
// nothing => NOT latency/MLP-bound. Shared trait of both flat versions: every
// (block,wave) reads 100 separate 1KB rows at 256KB stride => tens of thousands
// of tiny DRAM streams, row-buffer thrash. This version tiles 8 output rows per
// block so each (block,plane) read is 8KB CONTIGUOUS (8 back-to-back 1KB DMAs),
// 16x fewer streams, 8x longer runs.
#define Hd 256
#define Wd 256
#define Cc 4
#define KK 5
#define HT 8              // output rows per block
#define XWR (HT + KK - 1) // 12 x-window rows held in registers

typedef float v4f __attribute__((ext_vector_type(4)));

// 16-byte-per-lane async global->LDS DMA (wave-uniform LDS base + lane*16).
#define GLD16(gaddr, laddr)                                                          \
    __builtin_amdgcn_global_load_lds(                                                \
        (const __attribute__((address_space(1))) void*)(gaddr),                      \
        (__attribute__((address_space(3))) void*)(laddr), 16, 0, 0)

__global__ __launch_bounds__(256, 1) void dynf_kernel(const float* __restrict__ x,
                                                      const float* __restrict__ filt,
                                                      float* __restrict__ out) {
    // 256 blocks, 1 per CU. Bijective XCD swizzle (256%8==0): XCD k gets logical
    // blocks [k*32, (k+1)*32) => one batch b per XCD => x slice (1MB) L2-resident.
    const int bid  = blockIdx.x;
    const int lg   = ((bid & 7) << 5) + (bid >> 3);
    const int b    = lg >> 5;          // batch
    const int h0   = (lg & 31) << 3;   // first of 8 output rows
    const int c    = threadIdx.x >> 6; // wave id = channel (wave-uniform)
    const int lane = threadIdx.x & 63;
    const int w0   = lane << 2;

    const size_t HW = (size_t)Hd * Wd;

    // Double-buffered plane staging: [buf][channel][8 rows][256] = 64 KB.
    // Each wave touches only its own [c] slab => per-wave vmcnt suffices in-loop.
    __shared__ float lds[2][Cc][HT][Wd];

    const float* xc = x + ((size_t)b * Cc + c) * HW;
    const float* fb = filt + ((size_t)b * (Cc * KK * KK) + (size_t)c * (KK * KK)) * HW
                      + (size_t)h0 * Wd + w0;
    float* l0 = &lds[0][c][0][0];
    float* l1 = &lds[1][c][0][0];

    // ---- x window in registers: rows h0-2 .. h0+9, cols w0-2 .. w0+5.
    // All later indexing is compile-time constant (full unroll) => stays in VGPRs.
    float xw[XWR][8];
    const v4f vz = {0.f, 0.f, 0.f, 0.f};
#pragma unroll
    for (int ri = 0; ri < XWR; ++ri) {
        const int g = h0 + ri - 2;
        if (g >= 0 && g < Hd) {
            const float* xr = xc + (size_t)g * Wd;
            v4f left  = *(const v4f*)(xr + (w0 ? (w0 - 4) : 0));
            v4f mid   = *(const v4f*)(xr + w0);
            v4f right = *(const v4f*)(xr + ((w0 + 4 < Wd) ? (w0 + 4) : 0));
            if (w0 == 0)      left  = vz;
            if (w0 + 4 >= Wd) right = vz;
            xw[ri][0] = left.z;  xw[ri][1] = left.w;
            xw[ri][2] = mid.x;   xw[ri][3] = mid.y;
            xw[ri][4] = mid.z;   xw[ri][5] = mid.w;
            xw[ri][6] = right.x; xw[ri][7] = right.y;
        } else {
#pragma unroll
            for (int j = 0; j < 8; ++j) xw[ri][j] = 0.f;
        }
    }

    // ---- Prologue: stage plane 0 -> buf0, plane 1 -> buf1 (8KB contiguous each).
#pragma unroll
    for (int r = 0; r < HT; ++r) GLD16(fb + (size_t)r * Wd, l0 + r * Wd);
    asm volatile("" ::: "memory");
#pragma unroll
    for (int r = 0; r < HT; ++r) GLD16(fb + HW + (size_t)r * Wd, l1 + r * Wd);
    asm volatile("" ::: "memory");

    v4f acc[HT];
#pragma unroll
    for (int r = 0; r < HT; ++r) acc[r] = vz;

    // ---- Main loop over the 25 filter positions (planes), 2-deep pipeline.
#pragma unroll
    for (int p = 0; p < KK * KK; ++p) {
        // Newest 8 outstanding DMAs = next plane; everything older (this plane +
        // prologue x loads) is complete.
        if (p < KK * KK - 1) asm volatile("s_waitcnt vmcnt(8)" ::: "memory");
        else                 asm volatile("s_waitcnt vmcnt(0)" ::: "memory");

        const int di = p / KK, dj = p % KK;
        const float* ls = (p & 1) ? l1 : l0;
#pragma unroll
        for (int r = 0; r < HT; ++r) {
            v4f f = *(const v4f*)(ls + r * Wd + w0);
            acc[r].x = fmaf(xw[r + di][0 + dj], f.x, acc[r].x);
            acc[r].y = fmaf(xw[r + di][1 + dj], f.y, acc[r].y);
            acc[r].z = fmaf(xw[r + di][2 + dj], f.z, acc[r].z);
            acc[r].w = fmaf(xw[r + di][3 + dj], f.w, acc[r].w);
        }

        if (p + 2 < KK * KK) {
            // Drain LDS reads of this buffer, then reuse it for plane p+2.
            asm volatile("s_waitcnt lgkmcnt(0)" ::: "memory");
            float* ld = (p & 1) ? l1 : l0;
#pragma unroll
            for (int r = 0; r < HT; ++r)
                GLD16(fb + (size_t)(p + 2) * HW + (size_t)r * Wd, ld + r * Wd);
            asm volatile("" ::: "memory");
        }
    }

    // ---- Cross-wave channel reduction (reuse LDS; all DMA drained at p=24).
    __syncthreads();
    v4f* red = (v4f*)&lds[0][0][0][0];   // [c][r][lane] v4f = 32 KB
#pragma unroll
    for (int r = 0; r < HT; ++r) red[(c * HT + r) * 64 + lane] = acc[r];
    __syncthreads();

    // Wave c writes output rows 2c and 2c+1.
#pragma unroll
    for (int rr = 0; rr < 2; ++rr) {
        const int r = c * 2 + rr;
        v4f s = red[(0 * HT + r) * 64 + lane] + red[(1 * HT + r) * 64 + lane]
              + red[(2 * HT + r) * 64 + lane] + red[(3 * HT + r) * 64 + lane];
        v4f o;
        o.x = tanhf(s.x); o.y = tanhf(s.y); o.z = tanhf(s.z); o.w = tanhf(s.w);
        __builtin_nontemporal_store(o, (v4f*)(out + (size_t)b * HW + (size_t)(h0 + r) * Wd + w0));
    }
}

extern "C" void kernel_launch(void* const* d_in, const int* in_sizes, int n_in,
                              void* d_out, int out_size, void* d_ws, size_t ws_size,
                              hipStream_t stream) {
    const float* x    = (const float*)d_in[0];   // [8,4,256,256]
    const float* filt = (const float*)d_in[1];   // [8,100,256,256]
    float* out        = (float*)d_out;           // [8,1,256,256]

    const int grid  = 256;   // one block per (b, 8-row tile), 1 per CU
    const int block = 256;   // 4 waves = 4 channels
    dynf_kernel<<<grid, block, 0, stream>>>(x, filt, out);
}

// Round 3
// 277.727 us; speedup vs baseline: 1.2153x; 1.2153x over previous
//
#include <hip/hip_runtime.h>
#include <math.h>

// x:    [B=8, C=4, H=256, W=256] f32
// filt: [B, C*25, H, W]          f32
// out:  [B, 1, H, W]             f32
// out[b,h,w] = tanh( sum_{c,p} x_pad[b,c,h+p/5-2, w+p%5-2] * filt[b,c*25+p,h,w] )
//
// Bench model: bench_dur = kernel_dur + ~204us fixed harness fills.
// r0 kernel ~72us (3.0 TB/s), r1 (DMA) ~85us, r2 (HT=8, 1 blk/CU) 133us --
// r2 spilled (VGPR=256 cap + 83MB scratch writes) and ran 4 waves/CU.
// r3: HT=4 row tile (4KB contiguous per wave-plane, 4x fewer DRAM streams than
// r0) with a register budget that CANNOT spill (xw 64 + acc 16), plain
// nontemporal loads (no DMA, no staging LDS), 512 blocks = 2/CU = 8 waves/CU.
#define Hd 256
#define Wd 256
#define Cc 4
#define KK 5
#define HT 4              // output rows per block (one per wave at reduction)
#define XWR (HT + KK - 1) // 8 x-window rows in registers

typedef float v4f __attribute__((ext_vector_type(4)));

__global__ __launch_bounds__(256, 2) void dynf_kernel(const float* __restrict__ x,
                                                      const float* __restrict__ filt,
                                                      float* __restrict__ out) {
    // 512 blocks. HW round-robins consecutive blockIdx across the 8 XCDs, so
    // bid&7 = XCD id. Remap so XCD k owns lg in [64k, 64k+64) = all 64 row-tiles
    // of batch k => each XCD streams exactly its own 1MB x-slice (L2-resident,
    // 25x reuse) and a disjoint 26MB filt slab.
    const int bid  = blockIdx.x;
    const int lg   = ((bid & 7) << 6) + (bid >> 3);
    const int b    = lg >> 6;          // batch == XCD id
    const int h0   = (lg & 63) << 2;   // first of 4 output rows
    const int c    = threadIdx.x >> 6; // wave id = channel (wave-uniform)
    const int lane = threadIdx.x & 63;
    const int w0   = lane << 2;

    const size_t HW = (size_t)Hd * Wd;
    const float* xc = x + ((size_t)b * Cc + c) * HW;
    const float* fb = filt + ((size_t)b * (Cc * KK * KK) + (size_t)c * (KK * KK)) * HW
                      + (size_t)h0 * Wd + w0;

    // ---- x window in registers: rows h0-2 .. h0+5, cols w0-2 .. w0+5.
    // 64 floats; all later indexing compile-time constant => stays in VGPRs.
    float xw[XWR][8];
    const v4f vz = {0.f, 0.f, 0.f, 0.f};
#pragma unroll
    for (int ri = 0; ri < XWR; ++ri) {
        const int g = h0 + ri - 2;
        if (g >= 0 && g < Hd) {
            const float* xr = xc + (size_t)g * Wd;
            v4f left  = *(const v4f*)(xr + (w0 ? (w0 - 4) : 0));
            v4f mid   = *(const v4f*)(xr + w0);
            v4f right = *(const v4f*)(xr + ((w0 + 4 < Wd) ? (w0 + 4) : 0));
            if (w0 == 0)      left  = vz;
            if (w0 + 4 >= Wd) right = vz;
            xw[ri][0] = left.z;  xw[ri][1] = left.w;
            xw[ri][2] = mid.x;   xw[ri][3] = mid.y;
            xw[ri][4] = mid.z;   xw[ri][5] = mid.w;
            xw[ri][6] = right.x; xw[ri][7] = right.y;
        } else {
#pragma unroll
            for (int j = 0; j < 8; ++j) xw[ri][j] = 0.f;
        }
    }

    v4f acc[HT];
#pragma unroll
    for (int r = 0; r < HT; ++r) acc[r] = vz;

    // ---- 25 filter planes. Per plane this wave reads 4KB CONTIGUOUS (4 rows
    // x 1KB, back-to-back load instructions). Full unroll lets the compiler
    // run loads of plane p+1 under the FMAs of plane p. nontemporal: filt has
    // zero reuse -- keep x resident in L1/L2 instead.
#pragma unroll
    for (int p = 0; p < KK * KK; ++p) {
        const int di = p / KK, dj = p % KK;
        const float* fp = fb + (size_t)p * HW;
#pragma unroll
        for (int r = 0; r < HT; ++r) {
            v4f f = __builtin_nontemporal_load((const v4f*)(fp + (size_t)r * Wd));
            acc[r].x = fmaf(xw[r + di][0 + dj], f.x, acc[r].x);
            acc[r].y = fmaf(xw[r + di][1 + dj], f.y, acc[r].y);
            acc[r].z = fmaf(xw[r + di][2 + dj], f.z, acc[r].z);
            acc[r].w = fmaf(xw[r + di][3 + dj], f.w, acc[r].w);
        }
    }

    // ---- Cross-wave channel reduction: 16KB LDS, b128 conflict-free.
    __shared__ v4f red[Cc][HT][64];
#pragma unroll
    for (int r = 0; r < HT; ++r) red[c][r][lane] = acc[r];
    __syncthreads();

    // Wave c produces output row h0+c.
    {
        const int r = c;
        v4f s = red[0][r][lane] + red[1][r][lane] + red[2][r][lane] + red[3][r][lane];
        v4f o;
        o.x = tanhf(s.x); o.y = tanhf(s.y); o.z = tanhf(s.z); o.w = tanhf(s.w);
        __builtin_nontemporal_store(o, (v4f*)(out + (size_t)b * HW + (size_t)(h0 + r) * Wd + w0));
    }
}

extern "C" void kernel_launch(void* const* d_in, const int* in_sizes, int n_in,
                              void* d_out, int out_size, void* d_ws, size_t ws_size,
                              hipStream_t stream) {
    const float* x    = (const float*)d_in[0];   // [8,4,256,256]
    const float* filt = (const float*)d_in[1];   // [8,100,256,256]
    float* out        = (float*)d_out;           // [8,1,256,256]

    const int grid  = 512;   // (b, 4-row tile): 8 batches x 64 tiles, 2 blocks/CU
    const int block = 256;   // 4 waves = 4 channels
    dynf_kernel<<<grid, block, 0, stream>>>(x, filt, out);
}